// Round 1
// baseline (990.958 us; speedup 1.0000x reference)
//
#include <hip/hip_runtime.h>
#include <math.h>

// Problem constants (B=8, H=W=56, C=256)
constexpr int C_DIM = 256;
constexpr int MROWS = 25088;   // B*H*W
constexpr int HID   = 1024;

// ---------------- LayerNorm: one block per row, 256 threads ----------------
__global__ __launch_bounds__(256) void ln_kernel(
    const float* __restrict__ x, const float* __restrict__ g,
    const float* __restrict__ b, float* __restrict__ out)
{
    int row = blockIdx.x;
    int t = threadIdx.x;
    float v = x[(size_t)row * C_DIM + t];
    __shared__ float s1[256];
    __shared__ float s2[256];
    s1[t] = v; s2[t] = v * v;
    __syncthreads();
    #pragma unroll
    for (int off = 128; off > 0; off >>= 1) {
        if (t < off) { s1[t] += s1[t + off]; s2[t] += s2[t + off]; }
        __syncthreads();
    }
    float mu  = s1[0] * (1.0f / C_DIM);
    float var = s2[0] * (1.0f / C_DIM) - mu * mu;
    float inv = rsqrtf(var + 1e-5f);
    out[(size_t)row * C_DIM + t] = (v - mu) * inv * g[t] + b[t];
}

// ---------------- Tiled f32 GEMM: C = A[M,K] @ B[K,N] (+epilogue) ----------------
// FUSE: 0 = plain, 1 = +bias +residual(res), 2 = +bias +exact GELU
template<int FUSE>
__global__ __launch_bounds__(256) void gemm_kernel(
    const float* __restrict__ A, const float* __restrict__ Bw,
    const float* __restrict__ bias, const float* __restrict__ res,
    float* __restrict__ Cm, int M, int N, int K)
{
    constexpr int BM = 64, BN = 64, BK = 16;
    __shared__ __align__(16) float As[BK][BM + 4];  // +4 keeps float4 alignment (272B rows)
    __shared__ __align__(16) float Bs[BK][BN];
    int bn = blockIdx.x, bm = blockIdx.y;
    int row0 = bm * BM, col0 = bn * BN;
    int t  = threadIdx.x;
    int tx = t & 15, ty = t >> 4;

    float acc[4][4] = {};

    for (int k0 = 0; k0 < K; k0 += BK) {
        // stage A tile (64x16), transposed into As[k][m]
        int cA = t & 15;
        int rA = t >> 4;
        #pragma unroll
        for (int i = 0; i < 4; ++i) {
            int r = rA + 16 * i;
            As[cA][r] = A[(size_t)(row0 + r) * K + k0 + cA];
        }
        // stage B tile (16x64)
        int nB = t & 63;
        int kB = t >> 6;
        #pragma unroll
        for (int i = 0; i < 4; ++i) {
            int k = kB + 4 * i;
            Bs[k][nB] = Bw[(size_t)(k0 + k) * N + col0 + nB];
        }
        __syncthreads();
        #pragma unroll
        for (int k = 0; k < BK; ++k) {
            float4 a4 = *reinterpret_cast<const float4*>(&As[k][ty * 4]);
            float4 b4 = *reinterpret_cast<const float4*>(&Bs[k][tx * 4]);
            float a[4]  = {a4.x, a4.y, a4.z, a4.w};
            float bb[4] = {b4.x, b4.y, b4.z, b4.w};
            #pragma unroll
            for (int i = 0; i < 4; ++i)
                #pragma unroll
                for (int j = 0; j < 4; ++j)
                    acc[i][j] = fmaf(a[i], bb[j], acc[i][j]);
        }
        __syncthreads();
    }

    #pragma unroll
    for (int i = 0; i < 4; ++i) {
        int r = row0 + ty * 4 + i;
        #pragma unroll
        for (int j = 0; j < 4; ++j) {
            int cn = col0 + tx * 4 + j;
            float v = acc[i][j];
            if (FUSE >= 1) v += bias[cn];
            if (FUSE == 2) v = 0.5f * v * (1.0f + erff(v * 0.70710678118654752f));
            if (FUSE == 1) v += res[(size_t)r * N + cn];
            Cm[(size_t)r * N + cn] = v;
        }
    }
}

// ---------------- Windowed attention + fused LePE depthwise conv ----------------
// Grid: 512 blocks = 2 branches x 64 windows x 4 heads. Block: 448 threads.
// Each block: stage K,V (392x32 f32 each) in LDS; thread n = q-row n, online softmax.
__global__ __launch_bounds__(448) void attn_kernel(
    const float* __restrict__ qkv,   // [25088, 768], col = which*256 + c
    const float* __restrict__ c0w, const float* __restrict__ c0b,
    const float* __restrict__ c1w, const float* __restrict__ c1b,
    float* __restrict__ att)         // [25088, 256]
{
    __shared__ float kl[392 * 32];
    __shared__ float vl[392 * 32];

    int bid    = blockIdx.x;
    int branch = bid >> 8;       // 0: 56x7 stripes, 1: 7x56 stripes
    int rem    = bid & 255;
    int head   = rem & 3;
    int win    = rem >> 2;       // 0..63
    int b      = win >> 3;
    int wi     = win & 7;
    int Hsp = branch ? 7 : 56;
    int Wsp = branch ? 56 : 7;
    int c0  = branch * 128 + head * 32;   // channel base in the 256-wide qkv C dim
    const float* cw = branch ? c1w : c0w;
    const float* cb = branch ? c1b : c0b;
    int t = threadIdx.x;

    // stage K, V for this (window, head)
    for (int e = t; e < 392 * 32; e += 448) {
        int m  = e >> 5, dd = e & 31;
        int ii = branch ? (m / 56) : (m / 7);
        int jj = branch ? (m - ii * 56) : (m - ii * 7);
        int rrow = branch ? (wi * 7 + ii) : ii;
        int ccol = branch ? jj : (wi * 7 + jj);
        size_t base = ((size_t)(b * 3136) + rrow * 56 + ccol) * 768;
        kl[e] = qkv[base + 256 + c0 + dd];
        vl[e] = qkv[base + 512 + c0 + dd];
    }
    __syncthreads();

    if (t >= 392) return;   // no further barriers

    int n  = t;
    int ii = branch ? (n / 56) : (n / 7);
    int jj = branch ? (n - ii * 56) : (n - ii * 7);
    int rrow = branch ? (wi * 7 + ii) : ii;
    int ccol = branch ? jj : (wi * 7 + jj);
    size_t rowbase = (size_t)(b * 3136) + rrow * 56 + ccol;

    // q row -> registers, pre-scaled
    const float* qrow = qkv + rowbase * 768 + c0;
    float q[32];
    #pragma unroll
    for (int d4 = 0; d4 < 8; ++d4) {
        float4 f = reinterpret_cast<const float4*>(qrow)[d4];
        q[4*d4+0] = f.x; q[4*d4+1] = f.y; q[4*d4+2] = f.z; q[4*d4+3] = f.w;
    }
    const float scale = 0.17677669529663689f;  // 32^-0.5
    #pragma unroll
    for (int d = 0; d < 32; ++d) q[d] *= scale;

    // online softmax over 392 keys
    float mrun = -1e30f, lrun = 0.0f;
    float acc[32];
    #pragma unroll
    for (int d = 0; d < 32; ++d) acc[d] = 0.0f;

    for (int m = 0; m < 392; ++m) {
        const float* kr = &kl[m * 32];
        float s = 0.0f;
        #pragma unroll
        for (int d = 0; d < 32; ++d) s = fmaf(q[d], kr[d], s);
        if (s > mrun) {
            float f = __expf(mrun - s);
            lrun *= f;
            #pragma unroll
            for (int d = 0; d < 32; ++d) acc[d] *= f;
            mrun = s;
        }
        float p = __expf(s - mrun);
        lrun += p;
        const float* vr = &vl[m * 32];
        #pragma unroll
        for (int d = 0; d < 32; ++d) acc[d] = fmaf(p, vr[d], acc[d]);
    }
    float rinv = 1.0f / lrun;
    #pragma unroll
    for (int d = 0; d < 32; ++d) acc[d] *= rinv;

    // fused LePE: depthwise 3x3 over V inside the window (SAME, window-local zeros)
    int cbase = head * 32;
    #pragma unroll
    for (int kh = 0; kh < 3; ++kh) {
        int i2 = ii + kh - 1;
        if (i2 < 0 || i2 >= Hsp) continue;
        #pragma unroll
        for (int kw = 0; kw < 3; ++kw) {
            int j2 = jj + kw - 1;
            if (j2 < 0 || j2 >= Wsp) continue;
            const float* vr = &vl[(i2 * Wsp + j2) * 32];
            const float* wr = &cw[(kh * 3 + kw) * 128 + cbase];
            #pragma unroll
            for (int d = 0; d < 32; ++d) acc[d] = fmaf(wr[d], vr[d], acc[d]);
        }
    }
    #pragma unroll
    for (int d = 0; d < 32; ++d) acc[d] += cb[cbase + d];

    float* op = att + rowbase * 256 + branch * 128 + cbase;
    #pragma unroll
    for (int d4 = 0; d4 < 8; ++d4) {
        float4 f;
        f.x = acc[4*d4+0]; f.y = acc[4*d4+1]; f.z = acc[4*d4+2]; f.w = acc[4*d4+3];
        reinterpret_cast<float4*>(op)[d4] = f;
    }
}

// ---------------- launcher ----------------
extern "C" void kernel_launch(void* const* d_in, const int* in_sizes, int n_in,
                              void* d_out, int out_size, void* d_ws, size_t ws_size,
                              hipStream_t stream)
{
    const float* x      = (const float*)d_in[0];
    // d_in[1], d_in[2] are H, W (ints) — fixed at 56
    const float* n1g    = (const float*)d_in[3];
    const float* n1b    = (const float*)d_in[4];
    const float* qkv_w  = (const float*)d_in[5];
    const float* proj_w = (const float*)d_in[6];
    const float* proj_b = (const float*)d_in[7];
    const float* c0w    = (const float*)d_in[8];
    const float* c0b    = (const float*)d_in[9];
    const float* c1w    = (const float*)d_in[10];
    const float* c1b    = (const float*)d_in[11];
    const float* n2g    = (const float*)d_in[12];
    const float* n2b    = (const float*)d_in[13];
    const float* fc1_w  = (const float*)d_in[14];
    const float* fc1_b  = (const float*)d_in[15];
    const float* fc2_w  = (const float*)d_in[16];
    const float* fc2_b  = (const float*)d_in[17];
    float* out = (float*)d_out;

    char* ws = (char*)d_ws;
    const size_t SZ_MC = (size_t)MROWS * C_DIM * sizeof(float);  // 25,690,112 B
    float* img = (float*)(ws);                 // LN1 out, later LN2 out (y)
    float* att = (float*)(ws + SZ_MC);         // attention output [M, 256]
    float* big = (float*)(ws + 2 * SZ_MC);     // qkv [M,768], later hidden [M,1024]

    // 1. LN1
    ln_kernel<<<MROWS, 256, 0, stream>>>(x, n1g, n1b, img);
    // 2. qkv = img @ qkv_w   [25088 x 768 x 256]
    gemm_kernel<0><<<dim3(768 / 64, MROWS / 64), 256, 0, stream>>>(
        img, qkv_w, nullptr, nullptr, big, MROWS, 768, C_DIM);
    // 3. windowed attention + LePE (both branches)
    attn_kernel<<<512, 448, 0, stream>>>(big, c0w, c0b, c1w, c1b, att);
    // 4. xr = x + att @ proj_w + proj_b  -> d_out
    gemm_kernel<1><<<dim3(C_DIM / 64, MROWS / 64), 256, 0, stream>>>(
        att, proj_w, proj_b, x, out, MROWS, C_DIM, C_DIM);
    // 5. LN2 on xr -> y (reuse img)
    ln_kernel<<<MROWS, 256, 0, stream>>>(out, n2g, n2b, img);
    // 6. hidden = gelu(y @ fc1_w + fc1_b)
    gemm_kernel<2><<<dim3(HID / 64, MROWS / 64), 256, 0, stream>>>(
        img, fc1_w, fc1_b, nullptr, big, MROWS, HID, C_DIM);
    // 7. out = xr + hidden @ fc2_w + fc2_b  (residual read from d_out in place)
    gemm_kernel<1><<<dim3(C_DIM / 64, MROWS / 64), 256, 0, stream>>>(
        big, fc2_w, fc2_b, out, out, MROWS, C_DIM, HID);
}

// Round 2
// 394.945 us; speedup vs baseline: 2.5091x; 2.5091x over previous
//
#include <hip/hip_runtime.h>
#include <math.h>

constexpr int C_DIM = 256;
constexpr int MROWS = 25088;   // B*H*W
constexpr int HID   = 1024;

typedef float  f32x4 __attribute__((ext_vector_type(4)));
typedef short  s16x8 __attribute__((ext_vector_type(8)));

__device__ __forceinline__ ushort f2bf(float f) {
    unsigned u = __float_as_uint(f);
    unsigned r = (u + 0x7fffu + ((u >> 16) & 1u)) >> 16;
    return (ushort)r;
}
__device__ __forceinline__ float bf2f(ushort u) {
    return __uint_as_float(((unsigned)u) << 16);
}

// async global->LDS, 16B per lane; dest = wave-uniform base + lane*16
typedef const __attribute__((address_space(1))) unsigned guint;
typedef __attribute__((address_space(3))) unsigned luint;
__device__ __forceinline__ void gload16(const void* g, void* l) {
    __builtin_amdgcn_global_load_lds((guint*)g, (luint*)l, 16, 0, 0);
}

// ---------------- LayerNorm: one block per row, bf16 out ----------------
__global__ __launch_bounds__(256) void ln_kernel(
    const float* __restrict__ x, const float* __restrict__ g,
    const float* __restrict__ b, ushort* __restrict__ out)
{
    int row = blockIdx.x;
    int t = threadIdx.x;
    float v = x[(size_t)row * C_DIM + t];
    __shared__ float s1[256];
    __shared__ float s2[256];
    s1[t] = v; s2[t] = v * v;
    __syncthreads();
    #pragma unroll
    for (int off = 128; off > 0; off >>= 1) {
        if (t < off) { s1[t] += s1[t + off]; s2[t] += s2[t + off]; }
        __syncthreads();
    }
    float mu  = s1[0] * (1.0f / C_DIM);
    float var = s2[0] * (1.0f / C_DIM) - mu * mu;
    float inv = rsqrtf(var + 1e-5f);
    out[(size_t)row * C_DIM + t] = f2bf((v - mu) * inv * g[t] + b[t]);
}

// ---------------- weight transpose + cvt: w[K,N] f32 -> wT[N,K] bf16 ----------------
__global__ __launch_bounds__(256) void wcvt_kernel(
    const float* __restrict__ w, ushort* __restrict__ wT, int K, int N)
{
    __shared__ ushort tile[64][65];
    int n0 = blockIdx.x * 64, k0 = blockIdx.y * 64;
    int c = threadIdx.x & 63, rr = threadIdx.x >> 6;
    #pragma unroll
    for (int i = 0; i < 64; i += 4) {
        int r = i + rr;
        tile[r][c] = f2bf(w[(size_t)(k0 + r) * N + n0 + c]);
    }
    __syncthreads();
    #pragma unroll
    for (int i = 0; i < 64; i += 4) {
        int r = i + rr;   // output row n = n0+r, contiguous along k
        wT[(size_t)(n0 + r) * K + k0 + c] = tile[c][r];
    }
}

// ---------------- bf16 MFMA GEMM (m97 structure): C = A[M,K] @ Bt[N,K]^T ----------------
// FUSE: 0 = bf16 out; 1 = +bias +residual(f32), f32 out; 2 = +bias +GELU, bf16 out
template<int FUSE>
__global__ __launch_bounds__(256) void gemm_bf16(
    const ushort* __restrict__ A, const ushort* __restrict__ Bt,
    const float* __restrict__ bias, const float* res,
    void* Cout, int M, int N, int K)
{
    __shared__ ushort As[128 * 32];
    __shared__ ushort Bs[128 * 32];
    int tid  = threadIdx.x;
    int lane = tid & 63, wv = tid >> 6;
    int lr = lane & 15, lg = lane >> 4;
    int row0 = blockIdx.y * 128, col0 = blockIdx.x * 128;
    int wr = wv >> 1, wc = wv & 1;

    f32x4 acc[4][4];
    #pragma unroll
    for (int m = 0; m < 4; ++m)
        #pragma unroll
        for (int n = 0; n < 4; ++n)
            acc[m][n] = (f32x4){0.f, 0.f, 0.f, 0.f};

    int srow = wv * 32 + (lane >> 2);
    const ushort* gA  = A  + (size_t)(row0 + srow) * K + (lane & 3) * 8;
    const ushort* gA2 = gA + (size_t)16 * K;
    const ushort* gB  = Bt + (size_t)(col0 + srow) * K + (lane & 3) * 8;
    const ushort* gB2 = gB + (size_t)16 * K;
    ushort* lA  = &As[(wv * 32 +  0) * 32];
    ushort* lA2 = &As[(wv * 32 + 16) * 32];
    ushort* lB  = &Bs[(wv * 32 +  0) * 32];
    ushort* lB2 = &Bs[(wv * 32 + 16) * 32];

    for (int k0 = 0; k0 < K; k0 += 32) {
        gload16(gA  + k0, lA);
        gload16(gA2 + k0, lA2);
        gload16(gB  + k0, lB);
        gload16(gB2 + k0, lB2);
        __syncthreads();
        s16x8 af[4], bfg[4];
        #pragma unroll
        for (int m = 0; m < 4; ++m)
            af[m] = *(const s16x8*)&As[(wr * 64 + m * 16 + lr) * 32 + lg * 8];
        #pragma unroll
        for (int n = 0; n < 4; ++n)
            bfg[n] = *(const s16x8*)&Bs[(wc * 64 + n * 16 + lr) * 32 + lg * 8];
        #pragma unroll
        for (int m = 0; m < 4; ++m)
            #pragma unroll
            for (int n = 0; n < 4; ++n)
                acc[m][n] = __builtin_amdgcn_mfma_f32_16x16x32_bf16(af[m], bfg[n], acc[m][n], 0, 0, 0);
        __syncthreads();
    }

    int grow0 = row0 + wr * 64;
    int gcol0 = col0 + wc * 64;
    #pragma unroll
    for (int m = 0; m < 4; ++m) {
        #pragma unroll
        for (int n = 0; n < 4; ++n) {
            int gcol = gcol0 + n * 16 + lr;
            float bv = (FUSE >= 1) ? bias[gcol] : 0.0f;
            #pragma unroll
            for (int r = 0; r < 4; ++r) {
                int grow = grow0 + m * 16 + lg * 4 + r;
                float v = acc[m][n][r] + bv;
                if (FUSE == 2) v = 0.5f * v * (1.0f + erff(v * 0.70710678118654752f));
                if (FUSE == 1) {
                    v += res[(size_t)grow * N + gcol];
                    ((float*)Cout)[(size_t)grow * N + gcol] = v;
                } else {
                    ((ushort*)Cout)[(size_t)grow * N + gcol] = f2bf(v);
                }
            }
        }
    }
}

// ---------------- MFMA windowed attention + fused LePE ----------------
// grid 512 = 2 branch x 64 win x 4 head; 256 threads (4 waves split 25 q-tiles)
__device__ __forceinline__ int wrow(int branch, int b, int wi, int n) {
    if (branch) return b * 3136 + wi * 392 + n;
    int ii = n / 7;
    return b * 3136 + ii * 56 + wi * 7 + (n - ii * 7);
}

__global__ __launch_bounds__(256) void attn_kernel(
    const ushort* __restrict__ qkv,   // bf16 [M,768]
    const float* __restrict__ c0w, const float* __restrict__ c0b,
    const float* __restrict__ c1w, const float* __restrict__ c1b,
    ushort* __restrict__ att)         // bf16 [M,256]
{
    __shared__ ushort Kl[400][40];      // 32,000 B  (keys 0..399, rows 392+ zero)
    __shared__ ushort Vt[32][440];      // 28,160 B  (V^T: [d][key], cols 392+ zero)
    __shared__ ushort Pl[4][16][40];    //  5,120 B  (per-wave P tile [16q][32k])

    int bid    = blockIdx.x;
    int branch = bid >> 8;
    int rem    = bid & 255;
    int head   = rem & 3;
    int win    = rem >> 2;
    int b  = win >> 3, wi = win & 7;
    int c0 = branch * 128 + head * 32;
    const float* cw = branch ? c1w : c0w;
    const float* cb = branch ? c1b : c0b;
    int tid = threadIdx.x;

    // ---- stage K rows ----
    for (int e = tid; e < 1600; e += 256) {
        int n = e >> 2, ch = e & 3;
        uint4 v = make_uint4(0u, 0u, 0u, 0u);
        if (n < 392) {
            int gr = wrow(branch, b, wi, n);
            v = *(const uint4*)(qkv + (size_t)gr * 768 + 256 + c0 + ch * 8);
        }
        *(uint4*)&Kl[n][ch * 8] = v;
    }
    // ---- stage V transposed ----
    for (int e = tid; e < 1568; e += 256) {
        int n = e >> 2, ch = e & 3;
        int gr = wrow(branch, b, wi, n);
        uint4 v = *(const uint4*)(qkv + (size_t)gr * 768 + 512 + c0 + ch * 8);
        const ushort* us = (const ushort*)&v;
        #pragma unroll
        for (int j = 0; j < 8; ++j) Vt[ch * 8 + j][n] = us[j];
    }
    for (int e = tid; e < 32 * 48; e += 256) {
        int d = e / 48, k = 392 + (e - d * 48);
        Vt[d][k] = 0;
    }
    __syncthreads();

    int wv = tid >> 6, lane = tid & 63;
    int lr = lane & 15, lg = lane >> 4;
    const float scale = 0.17677669529663689f;
    ushort* Pw = &Pl[wv][0][0];

    // hoist conv weights / bias for this lane's two d-channels
    float wreg0[9], wreg1[9];
    #pragma unroll
    for (int tp = 0; tp < 9; ++tp) {
        wreg0[tp] = cw[tp * 128 + head * 32 + lr];
        wreg1[tp] = cw[tp * 128 + head * 32 + 16 + lr];
    }
    float cbr0 = cb[head * 32 + lr], cbr1 = cb[head * 32 + 16 + lr];
    int Hsp = branch ? 7 : 56, Wsp = branch ? 56 : 7;

    for (int qt = wv; qt < 25; qt += 4) {
        int q0 = qt * 16;
        int qn = q0 + lr; if (qn > 391) qn = 391;
        int qr = wrow(branch, b, wi, qn);
        s16x8 qf = *(const s16x8*)(qkv + (size_t)qr * 768 + c0 + lg * 8);

        f32x4 o0 = {0.f, 0.f, 0.f, 0.f}, o1 = {0.f, 0.f, 0.f, 0.f};
        float mrun[4], lrun[4];
        #pragma unroll
        for (int r = 0; r < 4; ++r) { mrun[r] = -1e30f; lrun[r] = 0.f; }

        auto do_chunk = [&](int c, bool last) {
            int t0 = c * 2;
            f32x4 zz = {0.f, 0.f, 0.f, 0.f};
            s16x8 kf0 = *(const s16x8*)&Kl[t0 * 16 + lr][lg * 8];
            f32x4 s0 = __builtin_amdgcn_mfma_f32_16x16x32_bf16(qf, kf0, zz, 0, 0, 0);
            f32x4 s1 = zz;
            if (!last) {
                s16x8 kf1 = *(const s16x8*)&Kl[t0 * 16 + 16 + lr][lg * 8];
                s1 = __builtin_amdgcn_mfma_f32_16x16x32_bf16(qf, kf1, zz, 0, 0, 0);
            }
            #pragma unroll
            for (int r = 0; r < 4; ++r) { s0[r] *= scale; s1[r] *= scale; }
            if (last) {
                #pragma unroll
                for (int r = 0; r < 4; ++r) {
                    if (lr >= 8) s0[r] = -1e30f;
                    s1[r] = -1e30f;
                }
            }
            float cm[4];
            #pragma unroll
            for (int r = 0; r < 4; ++r) cm[r] = fmaxf(s0[r], s1[r]);
            #pragma unroll
            for (int d = 1; d < 16; d <<= 1) {
                #pragma unroll
                for (int r = 0; r < 4; ++r)
                    cm[r] = fmaxf(cm[r], __shfl_xor(cm[r], d));
            }
            float rs[4];
            #pragma unroll
            for (int r = 0; r < 4; ++r) {
                float mnew = fmaxf(mrun[r], cm[r]);
                float f = __expf(mrun[r] - mnew);
                mrun[r] = mnew;
                lrun[r] *= f;
                o0[r] *= f; o1[r] *= f;
                float p0 = __expf(s0[r] - mnew);
                float p1 = __expf(s1[r] - mnew);
                rs[r] = p0 + p1;
                Pw[(lg * 4 + r) * 40 + lr]      = f2bf(p0);
                Pw[(lg * 4 + r) * 40 + 16 + lr] = f2bf(p1);
            }
            #pragma unroll
            for (int d = 1; d < 16; d <<= 1) {
                #pragma unroll
                for (int r = 0; r < 4; ++r)
                    rs[r] += __shfl_xor(rs[r], d);
            }
            #pragma unroll
            for (int r = 0; r < 4; ++r) lrun[r] += rs[r];

            s16x8 pf = *(const s16x8*)&Pw[lr * 40 + lg * 8];
            s16x8 v0 = *(const s16x8*)&Vt[lr][c * 32 + lg * 8];
            s16x8 v1 = *(const s16x8*)&Vt[16 + lr][c * 32 + lg * 8];
            o0 = __builtin_amdgcn_mfma_f32_16x16x32_bf16(pf, v0, o0, 0, 0, 0);
            o1 = __builtin_amdgcn_mfma_f32_16x16x32_bf16(pf, v1, o1, 0, 0, 0);
        };

        for (int c = 0; c < 12; ++c) do_chunk(c, false);
        do_chunk(12, true);

        #pragma unroll
        for (int r = 0; r < 4; ++r) {
            float rl = 1.0f / lrun[r];
            o0[r] *= rl; o1[r] *= rl;
        }

        // LePE conv + bias + store
        #pragma unroll
        for (int r = 0; r < 4; ++r) {
            int q = q0 + lg * 4 + r;
            if (q >= 392) continue;
            int ii = branch ? (q / 56) : (q / 7);
            int jj = q - ii * Wsp;
            float a0 = o0[r], a1 = o1[r];
            #pragma unroll
            for (int kh = 0; kh < 3; ++kh) {
                int i2 = ii + kh - 1;
                if ((unsigned)i2 >= (unsigned)Hsp) continue;
                #pragma unroll
                for (int kw = 0; kw < 3; ++kw) {
                    int j2 = jj + kw - 1;
                    if ((unsigned)j2 >= (unsigned)Wsp) continue;
                    int pos = i2 * Wsp + j2;
                    a0 += wreg0[kh * 3 + kw] * bf2f(Vt[lr][pos]);
                    a1 += wreg1[kh * 3 + kw] * bf2f(Vt[16 + lr][pos]);
                }
            }
            a0 += cbr0; a1 += cbr1;
            int gr = wrow(branch, b, wi, q);
            att[(size_t)gr * 256 + branch * 128 + head * 32 + lr]      = f2bf(a0);
            att[(size_t)gr * 256 + branch * 128 + head * 32 + 16 + lr] = f2bf(a1);
        }
    }
}

// ---------------- launcher ----------------
extern "C" void kernel_launch(void* const* d_in, const int* in_sizes, int n_in,
                              void* d_out, int out_size, void* d_ws, size_t ws_size,
                              hipStream_t stream)
{
    const float* x      = (const float*)d_in[0];
    const float* n1g    = (const float*)d_in[3];
    const float* n1b    = (const float*)d_in[4];
    const float* qkv_w  = (const float*)d_in[5];
    const float* proj_w = (const float*)d_in[6];
    const float* proj_b = (const float*)d_in[7];
    const float* c0w    = (const float*)d_in[8];
    const float* c0b    = (const float*)d_in[9];
    const float* c1w    = (const float*)d_in[10];
    const float* c1b    = (const float*)d_in[11];
    const float* n2g    = (const float*)d_in[12];
    const float* n2b    = (const float*)d_in[13];
    const float* fc1_w  = (const float*)d_in[14];
    const float* fc1_b  = (const float*)d_in[15];
    const float* fc2_w  = (const float*)d_in[16];
    const float* fc2_b  = (const float*)d_in[17];
    float* out = (float*)d_out;

    char* ws = (char*)d_ws;
    const size_t SZ_BF = (size_t)MROWS * C_DIM * 2;   // 12,845,056
    ushort* img  = (ushort*)(ws);
    ushort* att  = (ushort*)(ws + SZ_BF);
    ushort* big  = (ushort*)(ws + 2 * SZ_BF);               // qkv [M,768] / hidden [M,1024]
    char*   wbase = ws + 2 * SZ_BF + (size_t)MROWS * HID * 2;
    ushort* qkvT = (ushort*)(wbase);                        // [768][256]
    ushort* projT= (ushort*)(wbase +  393216);              // [256][256]
    ushort* fc1T = (ushort*)(wbase +  393216 + 131072);     // [1024][256]
    ushort* fc2T = (ushort*)(wbase +  393216 + 131072 + 524288); // [256][1024]

    // weights: transpose + cvt to bf16
    wcvt_kernel<<<dim3(768 / 64, 256 / 64), 256, 0, stream>>>(qkv_w, qkvT, 256, 768);
    wcvt_kernel<<<dim3(256 / 64, 256 / 64), 256, 0, stream>>>(proj_w, projT, 256, 256);
    wcvt_kernel<<<dim3(1024 / 64, 256 / 64), 256, 0, stream>>>(fc1_w, fc1T, 256, 1024);
    wcvt_kernel<<<dim3(256 / 64, 1024 / 64), 256, 0, stream>>>(fc2_w, fc2T, 1024, 256);

    // 1. LN1 -> img (bf16)
    ln_kernel<<<MROWS, 256, 0, stream>>>(x, n1g, n1b, img);
    // 2. qkv = img @ qkv_w  (bf16 out)
    gemm_bf16<0><<<dim3(768 / 128, MROWS / 128), 256, 0, stream>>>(
        img, qkvT, nullptr, nullptr, big, MROWS, 768, 256);
    // 3. attention + LePE -> att (bf16)
    attn_kernel<<<512, 256, 0, stream>>>(big, c0w, c0b, c1w, c1b, att);
    // 4. xr = x + att @ proj_w + proj_b -> d_out (f32)
    gemm_bf16<1><<<dim3(256 / 128, MROWS / 128), 256, 0, stream>>>(
        att, projT, proj_b, x, out, MROWS, 256, 256);
    // 5. LN2 -> img (bf16)
    ln_kernel<<<MROWS, 256, 0, stream>>>(out, n2g, n2b, img);
    // 6. hidden = gelu(img @ fc1_w + fc1_b) (bf16)
    gemm_bf16<2><<<dim3(HID / 128, MROWS / 128), 256, 0, stream>>>(
        img, fc1T, fc1_b, nullptr, big, MROWS, HID, 256);
    // 7. out = xr + hidden @ fc2_w + fc2_b (f32, in-place residual)
    gemm_bf16<1><<<dim3(256 / 128, MROWS / 128), 256, 0, stream>>>(
        big, fc2T, fc2_b, out, out, MROWS, 256, 1024);
}